// Round 1
// baseline (1019.484 us; speedup 1.0000x reference)
//
#include <hip/hip_runtime.h>

// Pipeline:
//  init -> hist(deg) -> dinv -> scan(CSR offsets) -> scatter(sort edges by dst)
//  -> gemm1 (h1 = x@W1; b1 cancels in BN) -> gather1 (agg1)
//  -> bn_stats -> bn_relu (in place on agg1)
//  -> gemm2 (h2 = y1@W2 into h1 buffer) -> gather2 (agg2 into agg1 buffer)
//  -> gstart (graph boundaries via binary search on sorted batch)
//  -> pool (+b2) -> head (Wg/Wr/Wc fused)

__global__ void init_kernel(int* __restrict__ counts, float* __restrict__ stats, int n) {
  int i = blockIdx.x * blockDim.x + threadIdx.x;
  if (i < n) counts[i] = 0;
  if (i < 256) stats[i] = 0.f;
}

__global__ void hist_kernel(const int* __restrict__ dst, int* __restrict__ counts, int e) {
  for (int i = blockIdx.x * blockDim.x + threadIdx.x; i < e; i += gridDim.x * blockDim.x)
    atomicAdd(&counts[dst[i]], 1);
}

__global__ void dinv_kernel(const int* __restrict__ counts, float* __restrict__ dinv, int n) {
  int i = blockIdx.x * blockDim.x + threadIdx.x;
  if (i < n) dinv[i] = rsqrtf((float)(counts[i] + 1));  // +1 self-loop; deg >= 1 always
}

// Single-block exclusive prefix scan of counts -> cursor. n up to ~100k.
__global__ __launch_bounds__(1024) void scan_kernel(const int* __restrict__ counts,
                                                    int* __restrict__ cursor, int n) {
  __shared__ int wsum[16];
  __shared__ int carry_s;
  int tid = threadIdx.x, lane = tid & 63, wid = tid >> 6;
  if (tid == 0) carry_s = 0;
  __syncthreads();
  for (int base = 0; base < n; base += 1024) {
    int idx = base + tid;
    int orig = (idx < n) ? counts[idx] : 0;
    int v = orig;
#pragma unroll
    for (int d = 1; d < 64; d <<= 1) {
      int t = __shfl_up(v, d, 64);
      if (lane >= d) v += t;
    }
    __syncthreads();                 // (A) prev iter fully consumed wsum/carry
    if (lane == 63) wsum[wid] = v;
    __syncthreads();                 // (B)
    if (wid == 0 && lane < 16) {
      int s = wsum[lane];
#pragma unroll
      for (int d = 1; d < 16; d <<= 1) {
        int t = __shfl_up(s, d, 64);
        if (lane >= d) s += t;
      }
      wsum[lane] = s;                // inclusive scan of wave sums
    }
    __syncthreads();                 // (C)
    int wexcl = (wid == 0) ? 0 : wsum[wid - 1];
    int excl = carry_s + wexcl + (v - orig);
    if (idx < n) cursor[idx] = excl;
    __syncthreads();                 // (D) all reads of carry_s/wsum done
    if (tid == 0) carry_s += wsum[15];
  }
}

__global__ void scatter_kernel(const int* __restrict__ src, const int* __restrict__ dst,
                               int* __restrict__ cursor, int* __restrict__ sorted_src, int e) {
  for (int i = blockIdx.x * blockDim.x + threadIdx.x; i < e; i += gridDim.x * blockDim.x) {
    int d = dst[i];
    int pos = atomicAdd(&cursor[d], 1);
    sorted_src[pos] = src[i];
  }
  // post: cursor[i] == row_end(i); row_beg(i) = cursor[i] - counts[i]
}

// C[n][128] = A[n][128] @ W[128][128].  One wave handles 8 rows; lane owns cols (lane, lane+64).
// W staged in LDS as float2 pairs; A rows read through scalar path (wave-uniform base).
__global__ __launch_bounds__(256) void gemm128_kernel(const float* __restrict__ A,
                                                      const float* __restrict__ W,
                                                      float* __restrict__ C, int n) {
  __shared__ float2 Wp[128 * 64];  // Wp[k*64+c] = {W[k][c], W[k][c+64]}  (64 KB)
  int tid = threadIdx.x;
  for (int idx = tid; idx < 128 * 64; idx += 256) {
    int k = idx >> 6, c = idx & 63;
    Wp[idx] = make_float2(W[k * 128 + c], W[k * 128 + c + 64]);
  }
  __syncthreads();
  int lane = tid & 63;
  int gw = (int)((blockIdx.x * 256u + tid) >> 6);
  int nw = (int)((gridDim.x * 256u) >> 6);
  for (int base = gw * 8; base < n; base += nw * 8) {
    int rem = n - base; if (rem > 8) rem = 8;
    int bs = __builtin_amdgcn_readfirstlane(base);
    const float* __restrict__ Ar = A + (size_t)bs * 128;
    float accx[8], accy[8];
#pragma unroll
    for (int i = 0; i < 8; ++i) { accx[i] = 0.f; accy[i] = 0.f; }
    if (rem == 8) {
      for (int k0 = 0; k0 < 128; k0 += 8) {
        float xs[8][8];
#pragma unroll
        for (int i = 0; i < 8; ++i)
#pragma unroll
          for (int kk = 0; kk < 8; ++kk)
            xs[i][kk] = Ar[i * 128 + k0 + kk];
#pragma unroll
        for (int kk = 0; kk < 8; ++kk) {
          float2 w = Wp[(k0 + kk) * 64 + lane];
#pragma unroll
          for (int i = 0; i < 8; ++i) {
            accx[i] = fmaf(xs[i][kk], w.x, accx[i]);
            accy[i] = fmaf(xs[i][kk], w.y, accy[i]);
          }
        }
      }
#pragma unroll
      for (int i = 0; i < 8; ++i) {
        C[(size_t)(base + i) * 128 + lane] = accx[i];
        C[(size_t)(base + i) * 128 + 64 + lane] = accy[i];
      }
    } else {
      for (int i = 0; i < rem; ++i) {
        float ax = 0.f, ay = 0.f;
        for (int k = 0; k < 128; ++k) {
          float xv = Ar[i * 128 + k];
          float2 w = Wp[k * 64 + lane];
          ax = fmaf(xv, w.x, ax);
          ay = fmaf(xv, w.y, ay);
        }
        C[(size_t)(base + i) * 128 + lane] = ax;
        C[(size_t)(base + i) * 128 + 64 + lane] = ay;
      }
    }
  }
}

// agg[i] = dinv[i] * ( sum_{e in row i} dinv[src_e]*h[src_e] + dinv[i]*h[i] )
// One wave per node; lane covers 2 channels (float2).
__global__ __launch_bounds__(256) void gather_kernel(const float* __restrict__ h,
    const int* __restrict__ srcs, const int* __restrict__ cursor,
    const int* __restrict__ counts, const float* __restrict__ dinv,
    float* __restrict__ out, int n) {
  int lane = threadIdx.x & 63;
  int gw = (int)((blockIdx.x * blockDim.x + threadIdx.x) >> 6);
  int nw = (int)((gridDim.x * blockDim.x) >> 6);
  for (int i0 = gw; i0 < n; i0 += nw) {
    int i = __builtin_amdgcn_readfirstlane(i0);
    int end = cursor[i];
    int cnt = counts[i];
    int beg = end - cnt;
    float di = dinv[i];
    const float2* __restrict__ hrow = (const float2*)(h + (size_t)i * 128);
    float2 hv = hrow[lane];
    float ax = di * hv.x, ay = di * hv.y;  // self-loop term (outer di applied at end)
    for (int e = beg; e < end; ++e) {
      int s = srcs[e];
      float w = dinv[s];
      const float2* __restrict__ hs = (const float2*)(h + (size_t)s * 128);
      float2 v = hs[lane];
      ax = fmaf(w, v.x, ax);
      ay = fmaf(w, v.y, ay);
    }
    float2 res; res.x = di * ax; res.y = di * ay;
    ((float2*)(out + (size_t)i * 128))[lane] = res;
  }
}

__global__ __launch_bounds__(256) void bn_stats_kernel(const float* __restrict__ a,
                                                       float* __restrict__ stats, int n) {
  int c = threadIdx.x & 127;
  int ph = threadIdx.x >> 7;  // 0/1
  float s = 0.f, q = 0.f;
  for (int r = blockIdx.x * 2 + ph; r < n; r += gridDim.x * 2) {
    float v = a[(size_t)r * 128 + c];
    s += v; q += v * v;
  }
  __shared__ float ls[256], lq[256];
  ls[threadIdx.x] = s; lq[threadIdx.x] = q;
  __syncthreads();
  if (threadIdx.x < 128) {
    s = ls[threadIdx.x] + ls[threadIdx.x + 128];
    q = lq[threadIdx.x] + lq[threadIdx.x + 128];
    atomicAdd(&stats[threadIdx.x], s);
    atomicAdd(&stats[128 + threadIdx.x], q);
  }
}

__global__ __launch_bounds__(256) void bn_relu_kernel(float* __restrict__ a,
    const float* __restrict__ stats, const float* __restrict__ gamma,
    const float* __restrict__ beta, int n) {
  int c = threadIdx.x & 127;
  float invN = 1.f / (float)n;
  float mu = stats[c] * invN;
  float var = stats[128 + c] * invN - mu * mu;
  float rstd = rsqrtf(var + 1e-5f);
  float sc = gamma[c] * rstd;
  float sh = beta[c] - mu * sc;
  size_t total = (size_t)n * 128;
  for (size_t i = blockIdx.x * (size_t)blockDim.x + threadIdx.x; i < total;
       i += (size_t)gridDim.x * blockDim.x) {
    float v = a[i];  // channel of i is (i & 127) == c since blockDim/stride are multiples of 128
    a[i] = fmaxf(fmaf(sc, v, sh), 0.f);
  }
}

__global__ void gstart_kernel(const int* __restrict__ batch, int* __restrict__ gstart,
                              int n, int G) {
  int g = blockIdx.x * blockDim.x + threadIdx.x;
  if (g > G) return;
  if (g == G) { gstart[g] = n; return; }
  int lo = 0, hi = n;
  while (lo < hi) {
    int mid = (lo + hi) >> 1;
    if (batch[mid] < g) lo = mid + 1; else hi = mid;
  }
  gstart[g] = lo;  // first index with batch[idx] >= g
}

__global__ __launch_bounds__(128) void pool_kernel(const float* __restrict__ a,
    const int* __restrict__ gstart, const float* __restrict__ b2,
    float* __restrict__ pooled, int G) {
  int g = blockIdx.x;
  int c = threadIdx.x;  // 128 threads
  int s = gstart[g], e = gstart[g + 1];
  float acc = 0.f;
  for (int r = s; r < e; ++r) acc += a[(size_t)r * 128 + c];
  int cnt = e - s;
  pooled[(size_t)g * 128 + c] = (cnt > 0) ? (acc / (float)cnt + b2[c]) : 0.f;
}

__global__ __launch_bounds__(128) void head_kernel(const float* __restrict__ pooled,
    const float* __restrict__ rst, const float* __restrict__ Wg, const float* __restrict__ bg,
    const float* __restrict__ Wr, const float* __restrict__ br, const float* __restrict__ Wc,
    const float* __restrict__ bc, float* __restrict__ out, int G) {
  int g = blockIdx.x;
  int t = threadIdx.x;
  __shared__ float xc[128];
  if (t < 64) {
    float acc = bg[t];
    const float* __restrict__ p = pooled + (size_t)g * 128;
    for (int k = 0; k < 128; ++k) acc = fmaf(p[k], Wg[k * 64 + t], acc);
    xc[t] = fmaxf(acc, 0.f);
  } else {
    int j = t - 64;
    float acc = br[j];
    const float* __restrict__ r = rst + (size_t)g * 64;
    for (int k = 0; k < 64; ++k) acc = fmaf(r[k], Wr[k * 64 + j], acc);
    xc[t] = fmaxf(acc, 0.f);
  }
  __syncthreads();
  if (t < 2) {
    float acc = bc[t];
    for (int j = 0; j < 128; ++j) acc = fmaf(xc[j], Wc[j * 2 + t], acc);
    out[(size_t)g * 2 + t] = acc;
  }
}

extern "C" void kernel_launch(void* const* d_in, const int* in_sizes, int n_in,
                              void* d_out, int out_size, void* d_ws, size_t ws_size,
                              hipStream_t stream) {
  (void)n_in; (void)ws_size;
  const float* x     = (const float*)d_in[0];
  const int*   ei    = (const int*)d_in[1];
  const int*   batch = (const int*)d_in[2];
  const float* rst   = (const float*)d_in[3];
  // d_in[4] = num_graphs scalar (use out_size/2)
  const float* W1    = (const float*)d_in[5];
  // d_in[6] = b1 — provably cancels in BatchNorm (mean subtraction), skipped
  const float* gamma = (const float*)d_in[7];
  const float* beta  = (const float*)d_in[8];
  const float* W2    = (const float*)d_in[9];
  const float* b2    = (const float*)d_in[10];
  const float* Wg    = (const float*)d_in[11];
  const float* bg    = (const float*)d_in[12];
  const float* Wr    = (const float*)d_in[13];
  const float* br    = (const float*)d_in[14];
  const float* Wc    = (const float*)d_in[15];
  const float* bc    = (const float*)d_in[16];
  float* out = (float*)d_out;

  int N = in_sizes[0] / 128;
  int E = in_sizes[1] / 2;
  int G = out_size / 2;
  const int* esrc = ei;
  const int* edst = ei + E;

  char* ws = (char*)d_ws;
  size_t off = 0;
  auto alloc = [&](size_t bytes) -> void* {
    void* p = ws + off;
    off += (bytes + 255) & ~(size_t)255;
    return p;
  };
  float* h1     = (float*)alloc((size_t)N * 128 * 4);  // h1, then reused as h2
  float* agg1   = (float*)alloc((size_t)N * 128 * 4);  // agg1 -> y1 (in place) -> agg2
  int* sorted   = (int*)alloc((size_t)E * 4);
  int* counts   = (int*)alloc((size_t)N * 4);
  int* cursor   = (int*)alloc((size_t)N * 4);
  float* dinv   = (float*)alloc((size_t)N * 4);
  float* stats  = (float*)alloc(256 * 4);
  int* gstart   = (int*)alloc((size_t)(G + 1) * 4);
  float* pooled = (float*)alloc((size_t)G * 128 * 4);

  int nb = (N + 255) / 256;
  init_kernel<<<nb, 256, 0, stream>>>(counts, stats, N);
  hist_kernel<<<1024, 256, 0, stream>>>(edst, counts, E);
  dinv_kernel<<<nb, 256, 0, stream>>>(counts, dinv, N);
  scan_kernel<<<1, 1024, 0, stream>>>(counts, cursor, N);
  scatter_kernel<<<1024, 256, 0, stream>>>(esrc, edst, cursor, sorted, E);

  gemm128_kernel<<<512, 256, 0, stream>>>(x, W1, h1, N);
  gather_kernel<<<4096, 256, 0, stream>>>(h1, sorted, cursor, counts, dinv, agg1, N);

  bn_stats_kernel<<<256, 256, 0, stream>>>(agg1, stats, N);
  bn_relu_kernel<<<1024, 256, 0, stream>>>(agg1, stats, gamma, beta, N);

  gemm128_kernel<<<512, 256, 0, stream>>>(agg1, W2, h1, N);          // h2 into h1 buffer
  gather_kernel<<<4096, 256, 0, stream>>>(h1, sorted, cursor, counts, dinv, agg1, N);  // agg2

  gstart_kernel<<<(G + 1 + 255) / 256, 256, 0, stream>>>(batch, gstart, N, G);
  pool_kernel<<<G, 128, 0, stream>>>(agg1, gstart, b2, pooled, G);
  head_kernel<<<G, 128, 0, stream>>>(pooled, rst, Wg, bg, Wr, br, Wc, bc, out, G);
}

// Round 2
// 811.969 us; speedup vs baseline: 1.2556x; 1.2556x over previous
//
#include <hip/hip_runtime.h>

// Pipeline:
//  init -> hist(deg, XCD-partitioned) -> dinv -> scan x3 (CSR offsets)
//  -> scatter (XCD-partitioned counting sort of edges by dst)
//  -> gemm1 (h1 = x@W1; b1 cancels in BN) -> gather1 (agg1)
//  -> bn_stats -> bn_relu (in place on agg1)
//  -> gemm2 (h2 = y1@W2 into h1 buffer) -> gather2 (agg2 into agg1 buffer)
//  -> gstart -> pool (+b2) -> head (Wg/Wr/Wc fused)

__global__ void init_kernel(int* __restrict__ counts, float* __restrict__ stats, int n) {
  int i = blockIdx.x * blockDim.x + threadIdx.x;
  if (i < n) counts[i] = 0;
  if (i < 256) stats[i] = 0.f;
}

// Partitioned histogram: block part = blockIdx&7; under round-robin dispatch this
// equals the XCD id, so counts[] lines for a dst-partition stay in one XCD's L2.
// Each edge is scanned by 8 blocks (same rank, parts 0..7), processed by exactly 1.
__global__ __launch_bounds__(256) void hist_kernel(const int* __restrict__ dst,
                                                   int* __restrict__ counts, int e, int n) {
  int part = blockIdx.x & 7;
  int rank = blockIdx.x >> 3;
  int nrank = gridDim.x >> 3;
  for (int i = rank * 256 + threadIdx.x; i < e; i += nrank * 256) {
    int d = __builtin_nontemporal_load(&dst[i]);
    int p = (int)((8u * (unsigned)d) / (unsigned)n);
    if (p == part) atomicAdd(&counts[d], 1);
  }
}

__global__ void dinv_kernel(const int* __restrict__ counts, float* __restrict__ dinv, int n) {
  int i = blockIdx.x * blockDim.x + threadIdx.x;
  if (i < n) dinv[i] = rsqrtf((float)(counts[i] + 1));  // +1 self-loop; deg >= 1 always
}

// ---- hierarchical exclusive scan of counts -> cursor ----
__global__ __launch_bounds__(1024) void scan1_kernel(const int* __restrict__ counts,
                                                     int* __restrict__ cursor,
                                                     int* __restrict__ bsum, int n) {
  __shared__ int wsum[16];
  int tid = threadIdx.x, lane = tid & 63, wid = tid >> 6;
  int idx = blockIdx.x * 1024 + tid;
  int orig = (idx < n) ? counts[idx] : 0;
  int v = orig;
#pragma unroll
  for (int d = 1; d < 64; d <<= 1) {
    int t = __shfl_up(v, d, 64);
    if (lane >= d) v += t;
  }
  if (lane == 63) wsum[wid] = v;
  __syncthreads();
  if (wid == 0 && lane < 16) {
    int s = wsum[lane];
#pragma unroll
    for (int d = 1; d < 16; d <<= 1) {
      int t = __shfl_up(s, d, 64);
      if (lane >= d) s += t;
    }
    wsum[lane] = s;  // inclusive scan of wave sums
  }
  __syncthreads();
  int wexcl = (wid == 0) ? 0 : wsum[wid - 1];
  if (idx < n) cursor[idx] = wexcl + (v - orig);
  if (tid == 0) bsum[blockIdx.x] = wsum[15];
}

__global__ __launch_bounds__(256) void scan2_kernel(const int* __restrict__ bsum,
                                                    int* __restrict__ boff, int nb) {
  __shared__ int wsum[4];
  int tid = threadIdx.x, lane = tid & 63, wid = tid >> 6;
  int orig = (tid < nb) ? bsum[tid] : 0;
  int v = orig;
#pragma unroll
  for (int d = 1; d < 64; d <<= 1) {
    int t = __shfl_up(v, d, 64);
    if (lane >= d) v += t;
  }
  if (lane == 63) wsum[wid] = v;
  __syncthreads();
  if (tid == 0) {
    int run = 0;
#pragma unroll
    for (int w = 0; w < 4; ++w) { int t = wsum[w]; wsum[w] = run; run += t; }
  }
  __syncthreads();
  if (tid < nb) boff[tid] = wsum[wid] + (v - orig);
}

__global__ void scan3_kernel(int* __restrict__ cursor, const int* __restrict__ boff, int n) {
  int i = blockIdx.x * blockDim.x + threadIdx.x;
  if (i < n) cursor[i] += boff[i >> 10];
}

// Partitioned counting-sort scatter. sorted positions for a dst-partition are a
// contiguous ~E/8 region -> one XCD's L2 assembles full 64B lines -> ~1x writeback.
__global__ __launch_bounds__(256) void scatter_kernel(const int* __restrict__ src,
                                                      const int* __restrict__ dst,
                                                      int* __restrict__ cursor,
                                                      int* __restrict__ sorted_src,
                                                      int e, int n) {
  int part = blockIdx.x & 7;
  int rank = blockIdx.x >> 3;
  int nrank = gridDim.x >> 3;
  for (int i = rank * 256 + threadIdx.x; i < e; i += nrank * 256) {
    int d = __builtin_nontemporal_load(&dst[i]);
    int p = (int)((8u * (unsigned)d) / (unsigned)n);
    if (p == part) {
      int s = __builtin_nontemporal_load(&src[i]);
      int pos = atomicAdd(&cursor[d], 1);
      sorted_src[pos] = s;
    }
  }
  // post: cursor[i] == row_end(i); row_beg(i) = cursor[i] - counts[i]
}

// C[n][128] = A[n][128] @ W[128][128].  One wave handles 8 rows; lane owns cols (lane, lane+64).
__global__ __launch_bounds__(256) void gemm128_kernel(const float* __restrict__ A,
                                                      const float* __restrict__ W,
                                                      float* __restrict__ C, int n) {
  __shared__ float2 Wp[128 * 64];  // Wp[k*64+c] = {W[k][c], W[k][c+64]}  (64 KB)
  int tid = threadIdx.x;
  for (int idx = tid; idx < 128 * 64; idx += 256) {
    int k = idx >> 6, c = idx & 63;
    Wp[idx] = make_float2(W[k * 128 + c], W[k * 128 + c + 64]);
  }
  __syncthreads();
  int lane = tid & 63;
  int gw = (int)((blockIdx.x * 256u + tid) >> 6);
  int nw = (int)((gridDim.x * 256u) >> 6);
  for (int base = gw * 8; base < n; base += nw * 8) {
    int rem = n - base; if (rem > 8) rem = 8;
    int bs = __builtin_amdgcn_readfirstlane(base);
    const float* __restrict__ Ar = A + (size_t)bs * 128;
    float accx[8], accy[8];
#pragma unroll
    for (int i = 0; i < 8; ++i) { accx[i] = 0.f; accy[i] = 0.f; }
    if (rem == 8) {
      for (int k0 = 0; k0 < 128; k0 += 8) {
        float xs[8][8];
#pragma unroll
        for (int i = 0; i < 8; ++i)
#pragma unroll
          for (int kk = 0; kk < 8; ++kk)
            xs[i][kk] = Ar[i * 128 + k0 + kk];
#pragma unroll
        for (int kk = 0; kk < 8; ++kk) {
          float2 w = Wp[(k0 + kk) * 64 + lane];
#pragma unroll
          for (int i = 0; i < 8; ++i) {
            accx[i] = fmaf(xs[i][kk], w.x, accx[i]);
            accy[i] = fmaf(xs[i][kk], w.y, accy[i]);
          }
        }
      }
#pragma unroll
      for (int i = 0; i < 8; ++i) {
        C[(size_t)(base + i) * 128 + lane] = accx[i];
        C[(size_t)(base + i) * 128 + 64 + lane] = accy[i];
      }
    } else {
      for (int i = 0; i < rem; ++i) {
        float ax = 0.f, ay = 0.f;
        for (int k = 0; k < 128; ++k) {
          float xv = Ar[i * 128 + k];
          float2 w = Wp[k * 64 + lane];
          ax = fmaf(xv, w.x, ax);
          ay = fmaf(xv, w.y, ay);
        }
        C[(size_t)(base + i) * 128 + lane] = ax;
        C[(size_t)(base + i) * 128 + 64 + lane] = ay;
      }
    }
  }
}

// agg[i] = dinv[i] * ( sum_{e in row i} dinv[src_e]*h[src_e] + dinv[i]*h[i] )
__global__ __launch_bounds__(256) void gather_kernel(const float* __restrict__ h,
    const int* __restrict__ srcs, const int* __restrict__ cursor,
    const int* __restrict__ counts, const float* __restrict__ dinv,
    float* __restrict__ out, int n) {
  int lane = threadIdx.x & 63;
  int gw = (int)((blockIdx.x * blockDim.x + threadIdx.x) >> 6);
  int nw = (int)((gridDim.x * blockDim.x) >> 6);
  for (int i0 = gw; i0 < n; i0 += nw) {
    int i = __builtin_amdgcn_readfirstlane(i0);
    int end = cursor[i];
    int cnt = counts[i];
    int beg = end - cnt;
    float di = dinv[i];
    const float2* __restrict__ hrow = (const float2*)(h + (size_t)i * 128);
    float2 hv = hrow[lane];
    float ax = di * hv.x, ay = di * hv.y;  // self-loop (outer di applied at end)
    int e = beg;
    if (e < end) {
      int s = srcs[e];  // software pipeline: next-src load overlaps current h row
      while (true) {
        int s_cur = s;
        ++e;
        if (e < end) s = srcs[e];
        float w = dinv[s_cur];
        const float2* __restrict__ hs = (const float2*)(h + (size_t)s_cur * 128);
        float2 v = hs[lane];
        ax = fmaf(w, v.x, ax);
        ay = fmaf(w, v.y, ay);
        if (e >= end) break;
      }
    }
    float2 res; res.x = di * ax; res.y = di * ay;
    ((float2*)(out + (size_t)i * 128))[lane] = res;
  }
}

__global__ __launch_bounds__(256) void bn_stats_kernel(const float* __restrict__ a,
                                                       float* __restrict__ stats, int n) {
  int c = threadIdx.x & 127;
  int ph = threadIdx.x >> 7;  // 0/1
  float s = 0.f, q = 0.f;
  for (int r = blockIdx.x * 2 + ph; r < n; r += gridDim.x * 2) {
    float v = a[(size_t)r * 128 + c];
    s += v; q += v * v;
  }
  __shared__ float ls[256], lq[256];
  ls[threadIdx.x] = s; lq[threadIdx.x] = q;
  __syncthreads();
  if (threadIdx.x < 128) {
    s = ls[threadIdx.x] + ls[threadIdx.x + 128];
    q = lq[threadIdx.x] + lq[threadIdx.x + 128];
    atomicAdd(&stats[threadIdx.x], s);
    atomicAdd(&stats[128 + threadIdx.x], q);
  }
}

__global__ __launch_bounds__(256) void bn_relu_kernel(float* __restrict__ a,
    const float* __restrict__ stats, const float* __restrict__ gamma,
    const float* __restrict__ beta, int n) {
  int c = threadIdx.x & 127;
  float invN = 1.f / (float)n;
  float mu = stats[c] * invN;
  float var = stats[128 + c] * invN - mu * mu;
  float rstd = rsqrtf(var + 1e-5f);
  float sc = gamma[c] * rstd;
  float sh = beta[c] - mu * sc;
  size_t total = (size_t)n * 128;
  for (size_t i = blockIdx.x * (size_t)blockDim.x + threadIdx.x; i < total;
       i += (size_t)gridDim.x * blockDim.x) {
    float v = a[i];  // channel of i is (i & 127) == c (blockDim/stride multiples of 128)
    a[i] = fmaxf(fmaf(sc, v, sh), 0.f);
  }
}

__global__ void gstart_kernel(const int* __restrict__ batch, int* __restrict__ gstart,
                              int n, int G) {
  int g = blockIdx.x * blockDim.x + threadIdx.x;
  if (g > G) return;
  if (g == G) { gstart[g] = n; return; }
  int lo = 0, hi = n;
  while (lo < hi) {
    int mid = (lo + hi) >> 1;
    if (batch[mid] < g) lo = mid + 1; else hi = mid;
  }
  gstart[g] = lo;
}

// 256 threads: 2 row-phases x 2 independent accumulators -> 4 loads in flight.
__global__ __launch_bounds__(256) void pool_kernel(const float* __restrict__ a,
    const int* __restrict__ gstart, const float* __restrict__ b2,
    float* __restrict__ pooled, int G) {
  int g = blockIdx.x;
  int c = threadIdx.x & 127;
  int ph = threadIdx.x >> 7;  // 0/1
  int s = gstart[g], e = gstart[g + 1];
  float a0 = 0.f, a1 = 0.f;
  for (int r = s + ph; r < e; r += 4) {
    a0 += a[(size_t)r * 128 + c];
    if (r + 2 < e) a1 += a[(size_t)(r + 2) * 128 + c];
  }
  __shared__ float ls[256];
  ls[threadIdx.x] = a0 + a1;
  __syncthreads();
  if (threadIdx.x < 128) {
    float acc = ls[threadIdx.x] + ls[threadIdx.x + 128];
    int cnt = e - s;
    pooled[(size_t)g * 128 + c] = (cnt > 0) ? (acc / (float)cnt + b2[c]) : 0.f;
  }
}

__global__ __launch_bounds__(128) void head_kernel(const float* __restrict__ pooled,
    const float* __restrict__ rst, const float* __restrict__ Wg, const float* __restrict__ bg,
    const float* __restrict__ Wr, const float* __restrict__ br, const float* __restrict__ Wc,
    const float* __restrict__ bc, float* __restrict__ out, int G) {
  int g = blockIdx.x;
  int t = threadIdx.x;
  __shared__ float xc[128];
  if (t < 64) {
    float acc = bg[t];
    const float* __restrict__ p = pooled + (size_t)g * 128;
    for (int k = 0; k < 128; ++k) acc = fmaf(p[k], Wg[k * 64 + t], acc);
    xc[t] = fmaxf(acc, 0.f);
  } else {
    int j = t - 64;
    float acc = br[j];
    const float* __restrict__ r = rst + (size_t)g * 64;
    for (int k = 0; k < 64; ++k) acc = fmaf(r[k], Wr[k * 64 + j], acc);
    xc[t] = fmaxf(acc, 0.f);
  }
  __syncthreads();
  if (t < 2) {
    float acc = bc[t];
    for (int j = 0; j < 128; ++j) acc = fmaf(xc[j], Wc[j * 2 + t], acc);
    out[(size_t)g * 2 + t] = acc;
  }
}

extern "C" void kernel_launch(void* const* d_in, const int* in_sizes, int n_in,
                              void* d_out, int out_size, void* d_ws, size_t ws_size,
                              hipStream_t stream) {
  (void)n_in; (void)ws_size;
  const float* x     = (const float*)d_in[0];
  const int*   ei    = (const int*)d_in[1];
  const int*   batch = (const int*)d_in[2];
  const float* rst   = (const float*)d_in[3];
  const float* W1    = (const float*)d_in[5];
  // d_in[6] = b1 — cancels in BatchNorm, skipped
  const float* gamma = (const float*)d_in[7];
  const float* beta  = (const float*)d_in[8];
  const float* W2    = (const float*)d_in[9];
  const float* b2    = (const float*)d_in[10];
  const float* Wg    = (const float*)d_in[11];
  const float* bg    = (const float*)d_in[12];
  const float* Wr    = (const float*)d_in[13];
  const float* br    = (const float*)d_in[14];
  const float* Wc    = (const float*)d_in[15];
  const float* bc    = (const float*)d_in[16];
  float* out = (float*)d_out;

  int N = in_sizes[0] / 128;
  int E = in_sizes[1] / 2;
  int G = out_size / 2;
  const int* esrc = ei;
  const int* edst = ei + E;

  char* ws = (char*)d_ws;
  size_t off = 0;
  auto alloc = [&](size_t bytes) -> void* {
    void* p = ws + off;
    off += (bytes + 255) & ~(size_t)255;
    return p;
  };
  float* h1     = (float*)alloc((size_t)N * 128 * 4);
  float* agg1   = (float*)alloc((size_t)N * 128 * 4);
  int* sorted   = (int*)alloc((size_t)E * 4);
  int* counts   = (int*)alloc((size_t)N * 4);
  int* cursor   = (int*)alloc((size_t)N * 4);
  float* dinv   = (float*)alloc((size_t)N * 4);
  float* stats  = (float*)alloc(256 * 4);
  int* gstart   = (int*)alloc((size_t)(G + 1) * 4);
  float* pooled = (float*)alloc((size_t)G * 128 * 4);
  int* bsum     = (int*)alloc(256 * 4);
  int* boff     = (int*)alloc(256 * 4);

  int nb = (N + 255) / 256;
  int nscan = (N + 1023) / 1024;
  init_kernel<<<nb, 256, 0, stream>>>(counts, stats, N);
  hist_kernel<<<2048, 256, 0, stream>>>(edst, counts, E, N);
  dinv_kernel<<<nb, 256, 0, stream>>>(counts, dinv, N);
  scan1_kernel<<<nscan, 1024, 0, stream>>>(counts, cursor, bsum, N);
  scan2_kernel<<<1, 256, 0, stream>>>(bsum, boff, nscan);
  scan3_kernel<<<(N + 255) / 256, 256, 0, stream>>>(cursor, boff, N);
  scatter_kernel<<<2048, 256, 0, stream>>>(esrc, edst, cursor, sorted, E, N);

  gemm128_kernel<<<512, 256, 0, stream>>>(x, W1, h1, N);
  gather_kernel<<<4096, 256, 0, stream>>>(h1, sorted, cursor, counts, dinv, agg1, N);

  bn_stats_kernel<<<512, 256, 0, stream>>>(agg1, stats, N);
  bn_relu_kernel<<<1024, 256, 0, stream>>>(agg1, stats, gamma, beta, N);

  gemm128_kernel<<<512, 256, 0, stream>>>(agg1, W2, h1, N);
  gather_kernel<<<4096, 256, 0, stream>>>(h1, sorted, cursor, counts, dinv, agg1, N);

  gstart_kernel<<<(G + 1 + 255) / 256, 256, 0, stream>>>(batch, gstart, N, G);
  pool_kernel<<<G, 256, 0, stream>>>(agg1, gstart, b2, pooled, G);
  head_kernel<<<G, 128, 0, stream>>>(pooled, rst, Wg, bg, Wr, br, Wc, bc, out, G);
}

// Round 3
// 655.861 us; speedup vs baseline: 1.5544x; 1.2380x over previous
//
#include <hip/hip_runtime.h>

// Pipeline:
//  init -> hist(deg, XCD-partitioned) -> dinv -> scan x3 (CSR offsets)
//  -> scatter (XCD-partitioned counting sort of edges by dst)
//  -> gemm1 (h1 = x@W1 -> bf16; b1 cancels in BN) -> gather1 (agg1 fp32)
//  -> bn_stats -> bn_relu (in place on agg1)
//  -> gemm2 (h2 = y1@W2 -> bf16) -> gather2 (agg2 fp32)
//  -> gstart -> pool (+b2) -> head (Wg/Wr/Wc fused)
//
// h stored as packed bf16 pairs (lane owns adjacent channels 2c,2c+1): halves
// the 870 MB of random row-gather traffic. Aggregation stays fp32; pooling
// averages ~195 rows so rounding errors wash out (~1e-3 final).

__device__ __forceinline__ float bf_lo(unsigned u) {
  union { unsigned u; float f; } c; c.u = u << 16; return c.f;
}
__device__ __forceinline__ float bf_hi(unsigned u) {
  union { unsigned u; float f; } c; c.u = u & 0xffff0000u; return c.f;
}
__device__ __forceinline__ unsigned pack_bf16(float a, float b) {
  union { float f; unsigned u; } ca, cb;
  ca.f = a; cb.f = b;
  unsigned ua = (ca.u + 0x7fffu + ((ca.u >> 16) & 1u)) >> 16;  // RNE
  unsigned ub = (cb.u + 0x7fffu + ((cb.u >> 16) & 1u)) >> 16;
  return ua | (ub << 16);
}

__global__ void init_kernel(int* __restrict__ counts, float* __restrict__ stats, int n) {
  int i = blockIdx.x * blockDim.x + threadIdx.x;
  if (i < n) counts[i] = 0;
  if (i < 256) stats[i] = 0.f;
}

// Partitioned histogram: block part = blockIdx&7 ~ XCD id under round-robin
// dispatch, so counts[] lines for a dst-partition stay in one XCD's L2.
__global__ __launch_bounds__(256) void hist_kernel(const int* __restrict__ dst,
                                                   int* __restrict__ counts, int e, int n) {
  int part = blockIdx.x & 7;
  int rank = blockIdx.x >> 3;
  int nrank = gridDim.x >> 3;
  for (int i = rank * 256 + threadIdx.x; i < e; i += nrank * 256) {
    int d = __builtin_nontemporal_load(&dst[i]);
    int p = (int)((8u * (unsigned)d) / (unsigned)n);
    if (p == part) atomicAdd(&counts[d], 1);
  }
}

__global__ void dinv_kernel(const int* __restrict__ counts, float* __restrict__ dinv, int n) {
  int i = blockIdx.x * blockDim.x + threadIdx.x;
  if (i < n) dinv[i] = rsqrtf((float)(counts[i] + 1));  // +1 self-loop
}

// ---- hierarchical exclusive scan of counts -> cursor ----
__global__ __launch_bounds__(1024) void scan1_kernel(const int* __restrict__ counts,
                                                     int* __restrict__ cursor,
                                                     int* __restrict__ bsum, int n) {
  __shared__ int wsum[16];
  int tid = threadIdx.x, lane = tid & 63, wid = tid >> 6;
  int idx = blockIdx.x * 1024 + tid;
  int orig = (idx < n) ? counts[idx] : 0;
  int v = orig;
#pragma unroll
  for (int d = 1; d < 64; d <<= 1) {
    int t = __shfl_up(v, d, 64);
    if (lane >= d) v += t;
  }
  if (lane == 63) wsum[wid] = v;
  __syncthreads();
  if (wid == 0 && lane < 16) {
    int s = wsum[lane];
#pragma unroll
    for (int d = 1; d < 16; d <<= 1) {
      int t = __shfl_up(s, d, 64);
      if (lane >= d) s += t;
    }
    wsum[lane] = s;
  }
  __syncthreads();
  int wexcl = (wid == 0) ? 0 : wsum[wid - 1];
  if (idx < n) cursor[idx] = wexcl + (v - orig);
  if (tid == 0) bsum[blockIdx.x] = wsum[15];
}

__global__ __launch_bounds__(256) void scan2_kernel(const int* __restrict__ bsum,
                                                    int* __restrict__ boff, int nb) {
  __shared__ int wsum[4];
  int tid = threadIdx.x, lane = tid & 63, wid = tid >> 6;
  int orig = (tid < nb) ? bsum[tid] : 0;
  int v = orig;
#pragma unroll
  for (int d = 1; d < 64; d <<= 1) {
    int t = __shfl_up(v, d, 64);
    if (lane >= d) v += t;
  }
  if (lane == 63) wsum[wid] = v;
  __syncthreads();
  if (tid == 0) {
    int run = 0;
#pragma unroll
    for (int w = 0; w < 4; ++w) { int t = wsum[w]; wsum[w] = run; run += t; }
  }
  __syncthreads();
  if (tid < nb) boff[tid] = wsum[wid] + (v - orig);
}

__global__ void scan3_kernel(int* __restrict__ cursor, const int* __restrict__ boff, int n) {
  int i = blockIdx.x * blockDim.x + threadIdx.x;
  if (i < n) cursor[i] += boff[i >> 10];
}

// Partitioned counting-sort scatter (write lines assembled within one XCD's L2).
__global__ __launch_bounds__(256) void scatter_kernel(const int* __restrict__ src,
                                                      const int* __restrict__ dst,
                                                      int* __restrict__ cursor,
                                                      int* __restrict__ sorted_src,
                                                      int e, int n) {
  int part = blockIdx.x & 7;
  int rank = blockIdx.x >> 3;
  int nrank = gridDim.x >> 3;
  for (int i = rank * 256 + threadIdx.x; i < e; i += nrank * 256) {
    int d = __builtin_nontemporal_load(&dst[i]);
    int p = (int)((8u * (unsigned)d) / (unsigned)n);
    if (p == part) {
      int s = __builtin_nontemporal_load(&src[i]);
      int pos = atomicAdd(&cursor[d], 1);
      sorted_src[pos] = s;
    }
  }
  // post: cursor[i] == row_end(i); row_beg(i) = cursor[i] - counts[i]
}

// Cb[n][64] (packed bf16 pairs) = A[n][128] @ W[128][128].
// One wave handles 8 rows; lane owns channels (2*lane, 2*lane+1).
__global__ __launch_bounds__(256) void gemm128_kernel(const float* __restrict__ A,
                                                      const float* __restrict__ W,
                                                      unsigned* __restrict__ Cb, int n) {
  __shared__ float2 Wp[128 * 64];  // Wp[k*64+c] = {W[k][2c], W[k][2c+1]}  (64 KB)
  int tid = threadIdx.x;
  for (int idx = tid; idx < 128 * 64; idx += 256) {
    int k = idx >> 6, c = idx & 63;
    Wp[idx] = make_float2(W[k * 128 + 2 * c], W[k * 128 + 2 * c + 1]);
  }
  __syncthreads();
  int lane = tid & 63;
  int gw = (int)((blockIdx.x * 256u + tid) >> 6);
  int nw = (int)((gridDim.x * 256u) >> 6);
  for (int base = gw * 8; base < n; base += nw * 8) {
    int rem = n - base; if (rem > 8) rem = 8;
    int bs = __builtin_amdgcn_readfirstlane(base);
    const float* __restrict__ Ar = A + (size_t)bs * 128;
    float accx[8], accy[8];
#pragma unroll
    for (int i = 0; i < 8; ++i) { accx[i] = 0.f; accy[i] = 0.f; }
    if (rem == 8) {
      for (int k0 = 0; k0 < 128; k0 += 8) {
        float xs[8][8];
#pragma unroll
        for (int i = 0; i < 8; ++i)
#pragma unroll
          for (int kk = 0; kk < 8; ++kk)
            xs[i][kk] = Ar[i * 128 + k0 + kk];
#pragma unroll
        for (int kk = 0; kk < 8; ++kk) {
          float2 w = Wp[(k0 + kk) * 64 + lane];
#pragma unroll
          for (int i = 0; i < 8; ++i) {
            accx[i] = fmaf(xs[i][kk], w.x, accx[i]);
            accy[i] = fmaf(xs[i][kk], w.y, accy[i]);
          }
        }
      }
#pragma unroll
      for (int i = 0; i < 8; ++i)
        Cb[(size_t)(base + i) * 64 + lane] = pack_bf16(accx[i], accy[i]);
    } else {
      for (int i = 0; i < rem; ++i) {
        float ax = 0.f, ay = 0.f;
        for (int k = 0; k < 128; ++k) {
          float xv = Ar[i * 128 + k];
          float2 w = Wp[k * 64 + lane];
          ax = fmaf(xv, w.x, ax);
          ay = fmaf(xv, w.y, ay);
        }
        Cb[(size_t)(base + i) * 64 + lane] = pack_bf16(ax, ay);
      }
    }
  }
}

// agg[i] = dinv[i] * ( sum_{e in row i} dinv[src_e]*h[src_e] + dinv[i]*h[i] )
// h is packed bf16 pairs [n][64]. Edge loop unrolled x4: 4 independent
// index->row load chains in flight per wave (latency-bound fix).
__global__ __launch_bounds__(256) void gather_kernel(const unsigned* __restrict__ h,
    const int* __restrict__ srcs, const int* __restrict__ cursor,
    const int* __restrict__ counts, const float* __restrict__ dinv,
    float* __restrict__ out, int n) {
  int lane = threadIdx.x & 63;
  int gw = (int)((blockIdx.x * blockDim.x + threadIdx.x) >> 6);
  int nw = (int)((gridDim.x * blockDim.x) >> 6);
  for (int i0 = gw; i0 < n; i0 += nw) {
    int i = __builtin_amdgcn_readfirstlane(i0);
    int end = cursor[i];
    int cnt = counts[i];
    int beg = end - cnt;
    float di = dinv[i];
    unsigned hv = h[(size_t)i * 64 + lane];
    float ax = di * bf_lo(hv), ay = di * bf_hi(hv);  // self-loop
    int e = beg;
    for (; e + 4 <= end; e += 4) {
      int s0 = srcs[e];       // wave-uniform -> scalar loads
      int s1 = srcs[e + 1];
      int s2 = srcs[e + 2];
      int s3 = srcs[e + 3];
      unsigned v0 = h[(size_t)s0 * 64 + lane];  // 4 independent row loads in flight
      unsigned v1 = h[(size_t)s1 * 64 + lane];
      unsigned v2 = h[(size_t)s2 * 64 + lane];
      unsigned v3 = h[(size_t)s3 * 64 + lane];
      float w0 = dinv[s0], w1 = dinv[s1], w2 = dinv[s2], w3 = dinv[s3];
      ax = fmaf(w0, bf_lo(v0), ax); ay = fmaf(w0, bf_hi(v0), ay);
      ax = fmaf(w1, bf_lo(v1), ax); ay = fmaf(w1, bf_hi(v1), ay);
      ax = fmaf(w2, bf_lo(v2), ax); ay = fmaf(w2, bf_hi(v2), ay);
      ax = fmaf(w3, bf_lo(v3), ax); ay = fmaf(w3, bf_hi(v3), ay);
    }
    for (; e < end; ++e) {
      int s = srcs[e];
      unsigned v = h[(size_t)s * 64 + lane];
      float w = dinv[s];
      ax = fmaf(w, bf_lo(v), ax);
      ay = fmaf(w, bf_hi(v), ay);
    }
    float2 res; res.x = di * ax; res.y = di * ay;  // lane owns ch 2*lane, 2*lane+1
    ((float2*)(out + (size_t)i * 128))[lane] = res;
  }
}

__global__ __launch_bounds__(256) void bn_stats_kernel(const float* __restrict__ a,
                                                       float* __restrict__ stats, int n) {
  int c = threadIdx.x & 127;
  int ph = threadIdx.x >> 7;
  float s = 0.f, q = 0.f;
  for (int r = blockIdx.x * 2 + ph; r < n; r += gridDim.x * 2) {
    float v = a[(size_t)r * 128 + c];
    s += v; q += v * v;
  }
  __shared__ float ls[256], lq[256];
  ls[threadIdx.x] = s; lq[threadIdx.x] = q;
  __syncthreads();
  if (threadIdx.x < 128) {
    s = ls[threadIdx.x] + ls[threadIdx.x + 128];
    q = lq[threadIdx.x] + lq[threadIdx.x + 128];
    atomicAdd(&stats[threadIdx.x], s);
    atomicAdd(&stats[128 + threadIdx.x], q);
  }
}

__global__ __launch_bounds__(256) void bn_relu_kernel(float* __restrict__ a,
    const float* __restrict__ stats, const float* __restrict__ gamma,
    const float* __restrict__ beta, int n) {
  int c = threadIdx.x & 127;
  float invN = 1.f / (float)n;
  float mu = stats[c] * invN;
  float var = stats[128 + c] * invN - mu * mu;
  float rstd = rsqrtf(var + 1e-5f);
  float sc = gamma[c] * rstd;
  float sh = beta[c] - mu * sc;
  size_t total = (size_t)n * 128;
  for (size_t i = blockIdx.x * (size_t)blockDim.x + threadIdx.x; i < total;
       i += (size_t)gridDim.x * blockDim.x) {
    float v = a[i];  // channel of i is (i & 127) == c
    a[i] = fmaxf(fmaf(sc, v, sh), 0.f);
  }
}

__global__ void gstart_kernel(const int* __restrict__ batch, int* __restrict__ gstart,
                              int n, int G) {
  int g = blockIdx.x * blockDim.x + threadIdx.x;
  if (g > G) return;
  if (g == G) { gstart[g] = n; return; }
  int lo = 0, hi = n;
  while (lo < hi) {
    int mid = (lo + hi) >> 1;
    if (batch[mid] < g) lo = mid + 1; else hi = mid;
  }
  gstart[g] = lo;
}

__global__ __launch_bounds__(256) void pool_kernel(const float* __restrict__ a,
    const int* __restrict__ gstart, const float* __restrict__ b2,
    float* __restrict__ pooled, int G) {
  int g = blockIdx.x;
  int c = threadIdx.x & 127;
  int ph = threadIdx.x >> 7;
  int s = gstart[g], e = gstart[g + 1];
  float a0 = 0.f, a1 = 0.f;
  for (int r = s + ph; r < e; r += 4) {
    a0 += a[(size_t)r * 128 + c];
    if (r + 2 < e) a1 += a[(size_t)(r + 2) * 128 + c];
  }
  __shared__ float ls[256];
  ls[threadIdx.x] = a0 + a1;
  __syncthreads();
  if (threadIdx.x < 128) {
    float acc = ls[threadIdx.x] + ls[threadIdx.x + 128];
    int cnt = e - s;
    pooled[(size_t)g * 128 + c] = (cnt > 0) ? (acc / (float)cnt + b2[c]) : 0.f;
  }
}

__global__ __launch_bounds__(128) void head_kernel(const float* __restrict__ pooled,
    const float* __restrict__ rst, const float* __restrict__ Wg, const float* __restrict__ bg,
    const float* __restrict__ Wr, const float* __restrict__ br, const float* __restrict__ Wc,
    const float* __restrict__ bc, float* __restrict__ out, int G) {
  int g = blockIdx.x;
  int t = threadIdx.x;
  __shared__ float xc[128];
  if (t < 64) {
    float acc = bg[t];
    const float* __restrict__ p = pooled + (size_t)g * 128;
    for (int k = 0; k < 128; ++k) acc = fmaf(p[k], Wg[k * 64 + t], acc);
    xc[t] = fmaxf(acc, 0.f);
  } else {
    int j = t - 64;
    float acc = br[j];
    const float* __restrict__ r = rst + (size_t)g * 64;
    for (int k = 0; k < 64; ++k) acc = fmaf(r[k], Wr[k * 64 + j], acc);
    xc[t] = fmaxf(acc, 0.f);
  }
  __syncthreads();
  if (t < 2) {
    float acc = bc[t];
    for (int j = 0; j < 128; ++j) acc = fmaf(xc[j], Wc[j * 2 + t], acc);
    out[(size_t)g * 2 + t] = acc;
  }
}

extern "C" void kernel_launch(void* const* d_in, const int* in_sizes, int n_in,
                              void* d_out, int out_size, void* d_ws, size_t ws_size,
                              hipStream_t stream) {
  (void)n_in; (void)ws_size;
  const float* x     = (const float*)d_in[0];
  const int*   ei    = (const int*)d_in[1];
  const int*   batch = (const int*)d_in[2];
  const float* rst   = (const float*)d_in[3];
  const float* W1    = (const float*)d_in[5];
  // d_in[6] = b1 — cancels in BatchNorm, skipped
  const float* gamma = (const float*)d_in[7];
  const float* beta  = (const float*)d_in[8];
  const float* W2    = (const float*)d_in[9];
  const float* b2    = (const float*)d_in[10];
  const float* Wg    = (const float*)d_in[11];
  const float* bg    = (const float*)d_in[12];
  const float* Wr    = (const float*)d_in[13];
  const float* br    = (const float*)d_in[14];
  const float* Wc    = (const float*)d_in[15];
  const float* bc    = (const float*)d_in[16];
  float* out = (float*)d_out;

  int N = in_sizes[0] / 128;
  int E = in_sizes[1] / 2;
  int G = out_size / 2;
  const int* esrc = ei;
  const int* edst = ei + E;

  char* ws = (char*)d_ws;
  size_t off = 0;
  auto alloc = [&](size_t bytes) -> void* {
    void* p = ws + off;
    off += (bytes + 255) & ~(size_t)255;
    return p;
  };
  unsigned* hb  = (unsigned*)alloc((size_t)N * 64 * 4);   // packed bf16 h (h1, then h2)
  float* agg1   = (float*)alloc((size_t)N * 128 * 4);     // agg1 -> y1 -> agg2
  int* sorted   = (int*)alloc((size_t)E * 4);
  int* counts   = (int*)alloc((size_t)N * 4);
  int* cursor   = (int*)alloc((size_t)N * 4);
  float* dinv   = (float*)alloc((size_t)N * 4);
  float* stats  = (float*)alloc(256 * 4);
  int* gstart   = (int*)alloc((size_t)(G + 1) * 4);
  float* pooled = (float*)alloc((size_t)G * 128 * 4);
  int* bsum     = (int*)alloc(256 * 4);
  int* boff     = (int*)alloc(256 * 4);

  int nb = (N + 255) / 256;
  int nscan = (N + 1023) / 1024;
  init_kernel<<<nb, 256, 0, stream>>>(counts, stats, N);
  hist_kernel<<<2048, 256, 0, stream>>>(edst, counts, E, N);
  dinv_kernel<<<nb, 256, 0, stream>>>(counts, dinv, N);
  scan1_kernel<<<nscan, 1024, 0, stream>>>(counts, cursor, bsum, N);
  scan2_kernel<<<1, 256, 0, stream>>>(bsum, boff, nscan);
  scan3_kernel<<<(N + 255) / 256, 256, 0, stream>>>(cursor, boff, N);
  scatter_kernel<<<2048, 256, 0, stream>>>(esrc, edst, cursor, sorted, E, N);

  gemm128_kernel<<<512, 256, 0, stream>>>(x, W1, hb, N);
  gather_kernel<<<4096, 256, 0, stream>>>(hb, sorted, cursor, counts, dinv, agg1, N);

  bn_stats_kernel<<<512, 256, 0, stream>>>(agg1, stats, N);
  bn_relu_kernel<<<1024, 256, 0, stream>>>(agg1, stats, gamma, beta, N);

  gemm128_kernel<<<512, 256, 0, stream>>>(agg1, W2, hb, N);
  gather_kernel<<<4096, 256, 0, stream>>>(hb, sorted, cursor, counts, dinv, agg1, N);

  gstart_kernel<<<(G + 1 + 255) / 256, 256, 0, stream>>>(batch, gstart, N, G);
  pool_kernel<<<G, 256, 0, stream>>>(agg1, gstart, b2, pooled, G);
  head_kernel<<<G, 128, 0, stream>>>(pooled, rst, Wg, bg, Wr, br, Wc, bc, out, G);
}

// Round 4
// 547.355 us; speedup vs baseline: 1.8626x; 1.1982x over previous
//
#include <hip/hip_runtime.h>

// Pipeline (all node features packed bf16 pairs; word c = channels 2c,2c+1):
//  init -> hist(deg, XCD-partitioned) -> dinv -> scan x3 (CSR offsets)
//  -> scatter (XCD-partitioned counting sort of edges by dst)
//  -> gemm_mfma<f32 A> (hb = bf16(x@W1); b1 cancels in BN)
//  -> gather (agg1b bf16) -> bn_stats -> bn_relu (yb bf16)
//  -> gemm_mfma<bf16 A> (hb = bf16(yb@W2)) -> gather (aggb bf16)
//  -> gstart -> pool (+b2, fp32 out) -> head

typedef __attribute__((ext_vector_type(8))) short bf16x8;
typedef __attribute__((ext_vector_type(4))) float f32x4;

__device__ __forceinline__ float bf_lo(unsigned u) {
  union { unsigned u; float f; } c; c.u = u << 16; return c.f;
}
__device__ __forceinline__ float bf_hi(unsigned u) {
  union { unsigned u; float f; } c; c.u = u & 0xffff0000u; return c.f;
}
__device__ __forceinline__ unsigned short f32_bf16(float f) {
  union { float f; unsigned u; } c; c.f = f;
  return (unsigned short)((c.u + 0x7fffu + ((c.u >> 16) & 1u)) >> 16);  // RNE
}
__device__ __forceinline__ unsigned pack_bf16(float a, float b) {
  return (unsigned)f32_bf16(a) | ((unsigned)f32_bf16(b) << 16);
}

__global__ void init_kernel(int* __restrict__ counts, float* __restrict__ stats, int n) {
  int i = blockIdx.x * blockDim.x + threadIdx.x;
  if (i < n) counts[i] = 0;
  if (i < 256) stats[i] = 0.f;
}

// Partitioned histogram: part = blockIdx&7 ~ XCD id under round-robin dispatch.
__global__ __launch_bounds__(256) void hist_kernel(const int* __restrict__ dst,
                                                   int* __restrict__ counts, int e, int n) {
  int part = blockIdx.x & 7;
  int rank = blockIdx.x >> 3;
  int nrank = gridDim.x >> 3;
  for (int i = rank * 256 + threadIdx.x; i < e; i += nrank * 256) {
    int d = __builtin_nontemporal_load(&dst[i]);
    int p = (int)((8u * (unsigned)d) / (unsigned)n);
    if (p == part) atomicAdd(&counts[d], 1);
  }
}

__global__ void dinv_kernel(const int* __restrict__ counts, float* __restrict__ dinv, int n) {
  int i = blockIdx.x * blockDim.x + threadIdx.x;
  if (i < n) dinv[i] = rsqrtf((float)(counts[i] + 1));  // +1 self-loop
}

// ---- hierarchical exclusive scan of counts -> cursor ----
__global__ __launch_bounds__(1024) void scan1_kernel(const int* __restrict__ counts,
                                                     int* __restrict__ cursor,
                                                     int* __restrict__ bsum, int n) {
  __shared__ int wsum[16];
  int tid = threadIdx.x, lane = tid & 63, wid = tid >> 6;
  int idx = blockIdx.x * 1024 + tid;
  int orig = (idx < n) ? counts[idx] : 0;
  int v = orig;
#pragma unroll
  for (int d = 1; d < 64; d <<= 1) {
    int t = __shfl_up(v, d, 64);
    if (lane >= d) v += t;
  }
  if (lane == 63) wsum[wid] = v;
  __syncthreads();
  if (wid == 0 && lane < 16) {
    int s = wsum[lane];
#pragma unroll
    for (int d = 1; d < 16; d <<= 1) {
      int t = __shfl_up(s, d, 64);
      if (lane >= d) s += t;
    }
    wsum[lane] = s;
  }
  __syncthreads();
  int wexcl = (wid == 0) ? 0 : wsum[wid - 1];
  if (idx < n) cursor[idx] = wexcl + (v - orig);
  if (tid == 0) bsum[blockIdx.x] = wsum[15];
}

__global__ __launch_bounds__(256) void scan2_kernel(const int* __restrict__ bsum,
                                                    int* __restrict__ boff, int nb) {
  __shared__ int wsum[4];
  int tid = threadIdx.x, lane = tid & 63, wid = tid >> 6;
  int orig = (tid < nb) ? bsum[tid] : 0;
  int v = orig;
#pragma unroll
  for (int d = 1; d < 64; d <<= 1) {
    int t = __shfl_up(v, d, 64);
    if (lane >= d) v += t;
  }
  if (lane == 63) wsum[wid] = v;
  __syncthreads();
  if (tid == 0) {
    int run = 0;
#pragma unroll
    for (int w = 0; w < 4; ++w) { int t = wsum[w]; wsum[w] = run; run += t; }
  }
  __syncthreads();
  if (tid < nb) boff[tid] = wsum[wid] + (v - orig);
}

__global__ void scan3_kernel(int* __restrict__ cursor, const int* __restrict__ boff, int n) {
  int i = blockIdx.x * blockDim.x + threadIdx.x;
  if (i < n) cursor[i] += boff[i >> 10];
}

// Partitioned counting-sort scatter (write lines assembled within one XCD's L2).
__global__ __launch_bounds__(256) void scatter_kernel(const int* __restrict__ src,
                                                      const int* __restrict__ dst,
                                                      int* __restrict__ cursor,
                                                      int* __restrict__ sorted_src,
                                                      int e, int n) {
  int part = blockIdx.x & 7;
  int rank = blockIdx.x >> 3;
  int nrank = gridDim.x >> 3;
  for (int i = rank * 256 + threadIdx.x; i < e; i += nrank * 256) {
    int d = __builtin_nontemporal_load(&dst[i]);
    int p = (int)((8u * (unsigned)d) / (unsigned)n);
    if (p == part) {
      int s = __builtin_nontemporal_load(&src[i]);
      int pos = atomicAdd(&cursor[d], 1);
      sorted_src[pos] = s;
    }
  }
  // post: cursor[i] == row_end(i); row_beg(i) = cursor[i] - counts[i]
}

// MFMA GEMM: Cb[n][64 words] = bf16(A[n][128] @ W[128][128]).
// One wave per 16-row tile; 8 col-tiles x 4 K-steps of mfma_f32_16x16x32_bf16.
// A-frag: lane(m=lane&15, q=lane>>4) holds A[m][q*8+j] -> 8 contiguous elems.
// B-frag: lane holds W[kt*32+q*8+j][ct*16+m] -> staged in LDS fragment-contiguous.
// C/D: col=lane&15, row=q*4+reg (verified layout) -> shfl_xor(1) pairs cols for
// packed-bf16 dword stores from even lanes.
template <bool ABF16>
__global__ __launch_bounds__(256) void gemm_mfma_kernel(const void* __restrict__ Ap,
                                                        const float* __restrict__ W,
                                                        unsigned* __restrict__ Cb, int n) {
  __shared__ unsigned short WB[16384];  // [kt][ct][nl][q][8 bf16] = 32 KB
  int tid = threadIdx.x;
  for (int idx = tid; idx < 16384; idx += 256) {
    int k = idx >> 7, c = idx & 127;  // W[k][c]
    int kt = k >> 5, q = (k >> 3) & 3, j = k & 7;
    int ct = c >> 4, nl = c & 15;
    WB[(((kt * 8 + ct) * 16 + nl) * 4 + q) * 8 + j] = f32_bf16(W[idx]);
  }
  __syncthreads();
  int lane = tid & 63;
  int m = lane & 15, q = lane >> 4;
  int wv = (int)((blockIdx.x * 256u + tid) >> 6);
  int nwv = (int)((gridDim.x * 256u) >> 6);
  int ntiles = n >> 4;  // n % 16 == 0 for this problem (100000)
  for (int t = wv; t < ntiles; t += nwv) {
    int row = t * 16 + m;
    bf16x8 af[4];
    if (ABF16) {
      const bf16x8* Ar = (const bf16x8*)((const unsigned*)Ap + (size_t)row * 64 + q * 4);
#pragma unroll
      for (int kt = 0; kt < 4; ++kt) af[kt] = Ar[kt * 4];  // +kt*64B
    } else {
      const float* Arow = (const float*)Ap + (size_t)row * 128 + q * 8;
#pragma unroll
      for (int kt = 0; kt < 4; ++kt) {
        f32x4 a0 = *(const f32x4*)(Arow + kt * 32);
        f32x4 a1 = *(const f32x4*)(Arow + kt * 32 + 4);
        union { bf16x8 v; unsigned short s[8]; } u;
        u.s[0] = f32_bf16(a0.x); u.s[1] = f32_bf16(a0.y);
        u.s[2] = f32_bf16(a0.z); u.s[3] = f32_bf16(a0.w);
        u.s[4] = f32_bf16(a1.x); u.s[5] = f32_bf16(a1.y);
        u.s[6] = f32_bf16(a1.z); u.s[7] = f32_bf16(a1.w);
        af[kt] = u.v;
      }
    }
    f32x4 acc[8];
#pragma unroll
    for (int ct = 0; ct < 8; ++ct) acc[ct] = (f32x4){0.f, 0.f, 0.f, 0.f};
#pragma unroll
    for (int kt = 0; kt < 4; ++kt) {
#pragma unroll
      for (int ct = 0; ct < 8; ++ct) {
        bf16x8 b = *(const bf16x8*)&WB[(((kt * 8 + ct) * 16 + m) * 4 + q) * 8];
        acc[ct] = __builtin_amdgcn_mfma_f32_16x16x32_bf16(af[kt], b, acc[ct], 0, 0, 0);
      }
    }
#pragma unroll
    for (int ct = 0; ct < 8; ++ct) {
#pragma unroll
      for (int r4 = 0; r4 < 4; ++r4) {
        float v = acc[ct][r4];
        float p = __shfl_xor(v, 1, 64);  // partner column
        if (!(m & 1)) {
          int r = t * 16 + q * 4 + r4;
          Cb[(size_t)r * 64 + ct * 8 + (m >> 1)] = pack_bf16(v, p);
        }
      }
    }
  }
}

// agg[i] = dinv[i] * ( sum_e dinv[src]*h[src] + dinv[i]*h[i] ); packed bf16 in/out.
// Edge loop unrolled x4 for 4 independent index->row load chains.
__global__ __launch_bounds__(256) void gather_kernel(const unsigned* __restrict__ h,
    const int* __restrict__ srcs, const int* __restrict__ cursor,
    const int* __restrict__ counts, const float* __restrict__ dinv,
    unsigned* __restrict__ out, int n) {
  int lane = threadIdx.x & 63;
  int gw = (int)((blockIdx.x * blockDim.x + threadIdx.x) >> 6);
  int nw = (int)((gridDim.x * blockDim.x) >> 6);
  for (int i0 = gw; i0 < n; i0 += nw) {
    int i = __builtin_amdgcn_readfirstlane(i0);
    int end = cursor[i];
    int cnt = counts[i];
    int beg = end - cnt;
    float di = dinv[i];
    unsigned hv = h[(size_t)i * 64 + lane];
    float ax = di * bf_lo(hv), ay = di * bf_hi(hv);  // self-loop
    int e = beg;
    for (; e + 4 <= end; e += 4) {
      int s0 = srcs[e];
      int s1 = srcs[e + 1];
      int s2 = srcs[e + 2];
      int s3 = srcs[e + 3];
      unsigned v0 = h[(size_t)s0 * 64 + lane];
      unsigned v1 = h[(size_t)s1 * 64 + lane];
      unsigned v2 = h[(size_t)s2 * 64 + lane];
      unsigned v3 = h[(size_t)s3 * 64 + lane];
      float w0 = dinv[s0], w1 = dinv[s1], w2 = dinv[s2], w3 = dinv[s3];
      ax = fmaf(w0, bf_lo(v0), ax); ay = fmaf(w0, bf_hi(v0), ay);
      ax = fmaf(w1, bf_lo(v1), ax); ay = fmaf(w1, bf_hi(v1), ay);
      ax = fmaf(w2, bf_lo(v2), ax); ay = fmaf(w2, bf_hi(v2), ay);
      ax = fmaf(w3, bf_lo(v3), ax); ay = fmaf(w3, bf_hi(v3), ay);
    }
    for (; e < end; ++e) {
      int s = srcs[e];
      unsigned v = h[(size_t)s * 64 + lane];
      float w = dinv[s];
      ax = fmaf(w, bf_lo(v), ax);
      ay = fmaf(w, bf_hi(v), ay);
    }
    out[(size_t)i * 64 + lane] = pack_bf16(di * ax, di * ay);
  }
}

__global__ __launch_bounds__(256) void bn_stats_kernel(const unsigned* __restrict__ a,
                                                       float* __restrict__ stats, int n) {
  int c2 = threadIdx.x & 63;
  int ph = threadIdx.x >> 6;  // 0..3
  float s0 = 0.f, s1 = 0.f, q0 = 0.f, q1 = 0.f;
  for (int r = blockIdx.x * 4 + ph; r < n; r += gridDim.x * 4) {
    unsigned v = a[(size_t)r * 64 + c2];
    float x0 = bf_lo(v), x1 = bf_hi(v);
    s0 += x0; s1 += x1; q0 += x0 * x0; q1 += x1 * x1;
  }
  __shared__ float ls[4][64][4];
  ls[ph][c2][0] = s0; ls[ph][c2][1] = s1; ls[ph][c2][2] = q0; ls[ph][c2][3] = q1;
  __syncthreads();
  if (threadIdx.x < 64) {
    int c = threadIdx.x;
    float S0 = 0.f, S1 = 0.f, Q0 = 0.f, Q1 = 0.f;
#pragma unroll
    for (int p = 0; p < 4; ++p) {
      S0 += ls[p][c][0]; S1 += ls[p][c][1]; Q0 += ls[p][c][2]; Q1 += ls[p][c][3];
    }
    atomicAdd(&stats[2 * c], S0);
    atomicAdd(&stats[2 * c + 1], S1);
    atomicAdd(&stats[128 + 2 * c], Q0);
    atomicAdd(&stats[129 + 2 * c], Q1);
  }
}

// y = bf16(relu(gamma*(a-mu)*rstd + beta)); packed in/out.
__global__ __launch_bounds__(256) void bn_relu_kernel(const unsigned* __restrict__ a,
    unsigned* __restrict__ yb, const float* __restrict__ stats,
    const float* __restrict__ gamma, const float* __restrict__ beta, int n) {
  __shared__ float sc[128], sh[128];
  int tid = threadIdx.x;
  if (tid < 128) {
    float invN = 1.f / (float)n;
    float mu = stats[tid] * invN;
    float var = stats[128 + tid] * invN - mu * mu;
    float rstd = rsqrtf(var + 1e-5f);
    float s = gamma[tid] * rstd;
    sc[tid] = s;
    sh[tid] = beta[tid] - mu * s;
  }
  __syncthreads();
  size_t total = (size_t)n * 64;
  for (size_t w = blockIdx.x * (size_t)blockDim.x + tid; w < total;
       w += (size_t)gridDim.x * blockDim.x) {
    int c2 = (int)(w & 63);
    unsigned v = a[w];
    float y0 = fmaxf(fmaf(sc[2 * c2], bf_lo(v), sh[2 * c2]), 0.f);
    float y1 = fmaxf(fmaf(sc[2 * c2 + 1], bf_hi(v), sh[2 * c2 + 1]), 0.f);
    yb[w] = pack_bf16(y0, y1);
  }
}

__global__ void gstart_kernel(const int* __restrict__ batch, int* __restrict__ gstart,
                              int n, int G) {
  int g = blockIdx.x * blockDim.x + threadIdx.x;
  if (g > G) return;
  if (g == G) { gstart[g] = n; return; }
  int lo = 0, hi = n;
  while (lo < hi) {
    int mid = (lo + hi) >> 1;
    if (batch[mid] < g) lo = mid + 1; else hi = mid;
  }
  gstart[g] = lo;
}

__global__ __launch_bounds__(256) void pool_kernel(const unsigned* __restrict__ a,
    const int* __restrict__ gstart, const float* __restrict__ b2,
    float* __restrict__ pooled, int G) {
  int g = blockIdx.x;
  int c2 = threadIdx.x & 63;
  int ph = threadIdx.x >> 6;  // 0..3
  int s = gstart[g], e = gstart[g + 1];
  float a0 = 0.f, a1 = 0.f;
  for (int r = s + ph; r < e; r += 4) {
    unsigned v = a[(size_t)r * 64 + c2];
    a0 += bf_lo(v); a1 += bf_hi(v);
  }
  __shared__ float ls[4][64][2];
  ls[ph][c2][0] = a0; ls[ph][c2][1] = a1;
  __syncthreads();
  if (threadIdx.x < 64) {
    int c = threadIdx.x;
    float S0 = 0.f, S1 = 0.f;
#pragma unroll
    for (int p = 0; p < 4; ++p) { S0 += ls[p][c][0]; S1 += ls[p][c][1]; }
    int cnt = e - s;
    float inv = (cnt > 0) ? 1.f / (float)cnt : 0.f;
    float2 res;
    res.x = (cnt > 0) ? (S0 * inv + b2[2 * c]) : 0.f;
    res.y = (cnt > 0) ? (S1 * inv + b2[2 * c + 1]) : 0.f;
    ((float2*)(pooled + (size_t)g * 128))[c] = res;
  }
}

__global__ __launch_bounds__(128) void head_kernel(const float* __restrict__ pooled,
    const float* __restrict__ rst, const float* __restrict__ Wg, const float* __restrict__ bg,
    const float* __restrict__ Wr, const float* __restrict__ br, const float* __restrict__ Wc,
    const float* __restrict__ bc, float* __restrict__ out, int G) {
  int g = blockIdx.x;
  int t = threadIdx.x;
  __shared__ float xc[128];
  if (t < 64) {
    float acc = bg[t];
    const float* __restrict__ p = pooled + (size_t)g * 128;
    for (int k = 0; k < 128; ++k) acc = fmaf(p[k], Wg[k * 64 + t], acc);
    xc[t] = fmaxf(acc, 0.f);
  } else {
    int j = t - 64;
    float acc = br[j];
    const float* __restrict__ r = rst + (size_t)g * 64;
    for (int k = 0; k < 64; ++k) acc = fmaf(r[k], Wr[k * 64 + j], acc);
    xc[t] = fmaxf(acc, 0.f);
  }
  __syncthreads();
  if (t < 2) {
    float acc = bc[t];
    for (int j = 0; j < 128; ++j) acc = fmaf(xc[j], Wc[j * 2 + t], acc);
    out[(size_t)g * 2 + t] = acc;
  }
}

extern "C" void kernel_launch(void* const* d_in, const int* in_sizes, int n_in,
                              void* d_out, int out_size, void* d_ws, size_t ws_size,
                              hipStream_t stream) {
  (void)n_in; (void)ws_size;
  const float* x     = (const float*)d_in[0];
  const int*   ei    = (const int*)d_in[1];
  const int*   batch = (const int*)d_in[2];
  const float* rst   = (const float*)d_in[3];
  const float* W1    = (const float*)d_in[5];
  // d_in[6] = b1 — cancels in BatchNorm, skipped
  const float* gamma = (const float*)d_in[7];
  const float* beta  = (const float*)d_in[8];
  const float* W2    = (const float*)d_in[9];
  const float* b2    = (const float*)d_in[10];
  const float* Wg    = (const float*)d_in[11];
  const float* bg    = (const float*)d_in[12];
  const float* Wr    = (const float*)d_in[13];
  const float* br    = (const float*)d_in[14];
  const float* Wc    = (const float*)d_in[15];
  const float* bc    = (const float*)d_in[16];
  float* out = (float*)d_out;

  int N = in_sizes[0] / 128;
  int E = in_sizes[1] / 2;
  int G = out_size / 2;
  const int* esrc = ei;
  const int* edst = ei + E;

  char* ws = (char*)d_ws;
  size_t off = 0;
  auto alloc = [&](size_t bytes) -> void* {
    void* p = ws + off;
    off += (bytes + 255) & ~(size_t)255;
    return p;
  };
  unsigned* hb  = (unsigned*)alloc((size_t)N * 64 * 4);  // packed bf16 h1/h2
  unsigned* agb = (unsigned*)alloc((size_t)N * 64 * 4);  // agg1b, reused as agg2b
  unsigned* yb  = (unsigned*)alloc((size_t)N * 64 * 4);  // bn+relu output
  int* sorted   = (int*)alloc((size_t)E * 4);
  int* counts   = (int*)alloc((size_t)N * 4);
  int* cursor   = (int*)alloc((size_t)N * 4);
  float* dinv   = (float*)alloc((size_t)N * 4);
  float* stats  = (float*)alloc(256 * 4);
  int* gstart   = (int*)alloc((size_t)(G + 1) * 4);
  float* pooled = (float*)alloc((size_t)G * 128 * 4);
  int* bsum     = (int*)alloc(256 * 4);
  int* boff     = (int*)alloc(256 * 4);

  int nb = (N + 255) / 256;
  int nscan = (N + 1023) / 1024;
  init_kernel<<<nb, 256, 0, stream>>>(counts, stats, N);
  hist_kernel<<<2048, 256, 0, stream>>>(edst, counts, E, N);
  dinv_kernel<<<nb, 256, 0, stream>>>(counts, dinv, N);
  scan1_kernel<<<nscan, 1024, 0, stream>>>(counts, cursor, bsum, N);
  scan2_kernel<<<1, 256, 0, stream>>>(bsum, boff, nscan);
  scan3_kernel<<<(N + 255) / 256, 256, 0, stream>>>(cursor, boff, N);
  scatter_kernel<<<2048, 256, 0, stream>>>(esrc, edst, cursor, sorted, E, N);

  gemm_mfma_kernel<false><<<1024, 256, 0, stream>>>(x, W1, hb, N);
  gather_kernel<<<4096, 256, 0, stream>>>(hb, sorted, cursor, counts, dinv, agb, N);

  bn_stats_kernel<<<512, 256, 0, stream>>>(agb, stats, N);
  bn_relu_kernel<<<2048, 256, 0, stream>>>(agb, yb, stats, gamma, beta, N);

  gemm_mfma_kernel<true><<<1024, 256, 0, stream>>>(yb, W2, hb, N);
  gather_kernel<<<4096, 256, 0, stream>>>(hb, sorted, cursor, counts, dinv, agb, N);

  gstart_kernel<<<(G + 1 + 255) / 256, 256, 0, stream>>>(batch, gstart, N, G);
  pool_kernel<<<G, 256, 0, stream>>>(agb, gstart, b2, pooled, G);
  head_kernel<<<G, 128, 0, stream>>>(pooled, rst, Wg, bg, Wr, br, Wc, bc, out, G);
}